// Round 8
// baseline (132.258 us; speedup 1.0000x reference)
//
#include <hip/hip_runtime.h>
#include <hip/hip_bf16.h>

typedef __attribute__((ext_vector_type(8))) short bf16x8;
typedef __attribute__((ext_vector_type(4))) float f32x4;
typedef __attribute__((ext_vector_type(4))) short s16x4;
typedef __attribute__((ext_vector_type(4))) int i32x4;

#define MFMA(a, b, c) __builtin_amdgcn_mfma_f32_16x16x32_bf16(a, b, c, 0, 0, 0)

#define SCALE_F 0.08838834764831845f  // (2*64)^-0.5

__device__ __forceinline__ short f2bf(float f) {
  __hip_bfloat16 h = __float2bfloat16(f);
  return *reinterpret_cast<short*>(&h);
}

__device__ __forceinline__ void gld_lds16(const void* g, void* s) {
  __builtin_amdgcn_global_load_lds(
      (const __attribute__((address_space(1))) void*)g,
      (__attribute__((address_space(3))) void*)s, 16, 0, 0);
}

// ---------------------------------------------------------------------------
// cast fp32 -> bf16, two tensors in one launch
__global__ void cast_bf16_dual(const float* __restrict__ a,
                               const float* __restrict__ b,
                               short* __restrict__ oa, short* __restrict__ ob,
                               int n) {
  int idx = (blockIdx.x * 256 + threadIdx.x) * 4;
  const float* src = a;
  short* dst = oa;
  if (idx >= n) { idx -= n; src = b; dst = ob; }
  float4 v = *(const float4*)&src[idx];
  s16x4 o;
  o.x = f2bf(v.x); o.y = f2bf(v.y); o.z = f2bf(v.z); o.w = f2bf(v.w);
  *(s16x4*)&dst[idx] = o;
}

// merged transpose-cast of all three weights (R=512 for all):
// Wq1[512,1536]->W1t, Wq2->W2t (Q-cols pre-scaled), Wo[512,512]->Wot
__global__ void cast_transpose3(const float* __restrict__ Wq1,
                                const float* __restrict__ Wq2,
                                const float* __restrict__ Wo,
                                short* __restrict__ W1t,
                                short* __restrict__ W2t,
                                short* __restrict__ Wot) {
  int i = blockIdx.x * 256 + threadIdx.x;
  const float* src;
  short* dst;
  int C;
  if (i < 786432) {
    src = Wq1; dst = W1t; C = 1536;
  } else if (i < 1572864) {
    i -= 786432; src = Wq2; dst = W2t; C = 1536;
  } else {
    i -= 1572864;
    if (i >= 262144) return;
    src = Wo; dst = Wot; C = 512;
  }
  int r = i / C, c = i % C;
  float v = src[i];
  if (C == 1536 && c < 512) v *= SCALE_F;  // fold SCALE into Q block
  dst[(size_t)c * 512 + r] = f2bf(v);
}

// ---------------------------------------------------------------------------
// Merged dual-stream QKV GEMM: C = x @ Wqkv for both streams in one launch.
// grid (32, 24): blockIdx.y < 12 -> stream 1, else stream 2.
__global__ __launch_bounds__(256) void gemm_qkv(
    const short* __restrict__ xb1, const short* __restrict__ xb2,
    const short* __restrict__ W1t, const short* __restrict__ W2t,
    short* __restrict__ QK1, short* __restrict__ QK2,
    short* __restrict__ Vt1, short* __restrict__ Vt2) {
  __shared__ short As[128 * 64];
  __shared__ short Bs[128 * 64];
  const int tid = threadIdx.x;
  const int w = tid >> 6, l = tid & 63;
  const int sid = blockIdx.y >= 12;
  const short* A = sid ? xb2 : xb1;
  const short* Bt = sid ? W2t : W1t;
  short* C0 = sid ? QK2 : QK1;
  short* C1 = sid ? Vt2 : Vt1;
  const int m0 = blockIdx.x * 128;
  const int n0 = (sid ? blockIdx.y - 12 : blockIdx.y) * 128;
  const int mi = (w >> 1) * 64, ni = (w & 1) * 64;
  const int lrow = l & 15, lk8 = (l >> 4) * 8;
  const int K = 512;

  f32x4 acc[4][4] = {};

  for (int k0 = 0; k0 < K; k0 += 64) {
    for (int g = 0; g < 4; ++g) {
      int c = g * 256 + w * 64 + l;
      int row = c >> 3, c8 = (c & 7) * 8;
      int ldsoff = (g * 256 + w * 64) * 8;
      gld_lds16(A + (size_t)(m0 + row) * K + k0 + c8, (void*)(As + ldsoff));
      gld_lds16(Bt + (size_t)(n0 + row) * K + k0 + c8, (void*)(Bs + ldsoff));
    }
    __syncthreads();
    __builtin_amdgcn_s_setprio(1);
    for (int kp = 0; kp < 2; ++kp) {
      bf16x8 af[4], bfr[4];
      for (int mf = 0; mf < 4; ++mf)
        af[mf] = *(const bf16x8*)&As[(mi + mf * 16 + lrow) * 64 + kp * 32 + lk8];
      for (int nf = 0; nf < 4; ++nf)
        bfr[nf] = *(const bf16x8*)&Bs[(ni + nf * 16 + lrow) * 64 + kp * 32 + lk8];
      for (int mf = 0; mf < 4; ++mf)
        for (int nf = 0; nf < 4; ++nf)
          acc[mf][nf] = MFMA(af[mf], bfr[nf], acc[mf][nf]);
    }
    __builtin_amdgcn_s_setprio(0);
    __syncthreads();
  }

  for (int mf = 0; mf < 4; ++mf)
    for (int nf = 0; nf < 4; ++nf)
      for (int r = 0; r < 4; ++r) {
        int row = m0 + mi + mf * 16 + (l >> 4) * 4 + r;
        int col = n0 + ni + nf * 16 + lrow;
        float v = acc[mf][nf][r];
        if (col < 1024) {
          C0[(size_t)row * 1024 + col] = f2bf(v);
        } else {
          int b = row >> 11, n = row & 2047;
          int cv = col - 1024, h = cv >> 6, d = cv & 63;
          C1[(((size_t)(b * 8 + h) * 64 + d) << 11) + n] = f2bf(v);
        }
      }
}

// ---------------------------------------------------------------------------
// Output-projection GEMM, 64x128 tile (512 blocks -> 2 blocks/CU):
// Cf[8192,512] = A[8192,512] @ Wot[512,512]^T + bias
__global__ __launch_bounds__(256) void gemm_out(const short* __restrict__ A,
                                                const short* __restrict__ Bt,
                                                float* __restrict__ Cf,
                                                const float* __restrict__ bias) {
  __shared__ short As[64 * 64];
  __shared__ short Bs[128 * 64];
  const int tid = threadIdx.x;
  const int w = tid >> 6, l = tid & 63;
  const int m0 = blockIdx.x * 64, n0 = blockIdx.y * 128;
  const int mi = (w >> 1) * 32, ni = (w & 1) * 64;
  const int lrow = l & 15, lk8 = (l >> 4) * 8;
  const int K = 512, N = 512;

  f32x4 acc[2][4] = {};

  for (int k0 = 0; k0 < K; k0 += 64) {
    for (int g = 0; g < 2; ++g) {
      int c = g * 256 + tid;
      int row = c >> 3, c8 = (c & 7) * 8;
      gld_lds16(A + (size_t)(m0 + row) * K + k0 + c8, (void*)(As + c * 8));
    }
    for (int g = 0; g < 4; ++g) {
      int c = g * 256 + tid;
      int row = c >> 3, c8 = (c & 7) * 8;
      gld_lds16(Bt + (size_t)(n0 + row) * K + k0 + c8, (void*)(Bs + c * 8));
    }
    __syncthreads();
    __builtin_amdgcn_s_setprio(1);
    for (int kp = 0; kp < 2; ++kp) {
      bf16x8 af[2], bfr[4];
      for (int mf = 0; mf < 2; ++mf)
        af[mf] = *(const bf16x8*)&As[(mi + mf * 16 + lrow) * 64 + kp * 32 + lk8];
      for (int nf = 0; nf < 4; ++nf)
        bfr[nf] = *(const bf16x8*)&Bs[(ni + nf * 16 + lrow) * 64 + kp * 32 + lk8];
      for (int mf = 0; mf < 2; ++mf)
        for (int nf = 0; nf < 4; ++nf)
          acc[mf][nf] = MFMA(af[mf], bfr[nf], acc[mf][nf]);
    }
    __builtin_amdgcn_s_setprio(0);
    __syncthreads();
  }

  for (int mf = 0; mf < 2; ++mf)
    for (int nf = 0; nf < 4; ++nf)
      for (int r = 0; r < 4; ++r) {
        int row = m0 + mi + mf * 16 + (l >> 4) * 4 + r;
        int col = n0 + ni + nf * 16 + lrow;
        Cf[(size_t)row * N + col] = acc[mf][nf][r] + bias[col];
      }
}

// ---------------------------------------------------------------------------
// Dual-stream flash attention, v7: 32 q-rows per wave (two 16-row groups A/B
// sharing every K/V fragment read). QBLK=128, 4 waves, grid(16,16)=256 blocks
// = 1 block/CU. K/V fragment LDS traffic per q-row HALVES vs v6; the two
// independent q-group chains provide intra-wave ILP in place of lost TLP.
// Sync skeleton (counted vmcnt(8), raw barriers), permuted-K staging, XOR
// swizzle identical to v6.
__global__ __launch_bounds__(256, 1) void attn_kernel(
    const short* __restrict__ QK1, const short* __restrict__ QK2,
    const short* __restrict__ Vt1, const short* __restrict__ Vt2,
    short* __restrict__ Ocat) {
  __shared__ short K1s[2][4096], K2s[2][4096], V1s[2][4096], V2s[2][4096];

  const int tid = threadIdx.x;
  const int w = tid >> 6, l = tid & 63;
  const int qb = blockIdx.x, bh = blockIdx.y;
  const int b = bh >> 3, h = bh & 7;
  const int lrow = l & 15, g4 = l >> 4, lk8 = g4 * 8;

  const short* Q1p = QK1 + (size_t)b * 2048 * 1024 + h * 64;
  const short* K1p = Q1p + 512;
  const short* Q2p = QK2 + (size_t)b * 2048 * 1024 + h * 64;
  const short* K2p = Q2p + 512;
  const short* V1p = Vt1 + (size_t)bh * 64 * 2048;
  const short* V2p = Vt2 + (size_t)bh * 64 * 2048;

  // two 16-row Q groups per wave, all fragments in registers
  const int qrowA = qb * 128 + w * 32 + lrow;
  const int qrowB = qrowA + 16;
  bf16x8 q1A0 = *(const bf16x8*)&Q1p[(size_t)qrowA * 1024 + lk8];
  bf16x8 q1A1 = *(const bf16x8*)&Q1p[(size_t)qrowA * 1024 + 32 + lk8];
  bf16x8 q2A0 = *(const bf16x8*)&Q2p[(size_t)qrowA * 1024 + lk8];
  bf16x8 q2A1 = *(const bf16x8*)&Q2p[(size_t)qrowA * 1024 + 32 + lk8];
  bf16x8 q1B0 = *(const bf16x8*)&Q1p[(size_t)qrowB * 1024 + lk8];
  bf16x8 q1B1 = *(const bf16x8*)&Q1p[(size_t)qrowB * 1024 + 32 + lk8];
  bf16x8 q2B0 = *(const bf16x8*)&Q2p[(size_t)qrowB * 1024 + lk8];
  bf16x8 q2B1 = *(const bf16x8*)&Q2p[(size_t)qrowB * 1024 + 32 + lk8];

  f32x4 o1A[4] = {}, o2A[4] = {}, o1B[4] = {}, o2B[4] = {};
  float mrA = -1e30f, lrA = 0.f, mrB = -1e30f, lrB = 0.f;

  // ---- staging bases: gg=1 (rows 32..63) derived by constant offsets ----
  const int cl0 = w * 64 + l;           // 16B chunk, gg=0 (rows 0..31)
  const int row0 = cl0 >> 3;
  const int lc0 = (cl0 & 7) ^ (row0 & 7);  // XOR swizzle (rule 21)
  // pi-permuted K row (row0<32 -> row0>>5 term = 0); perm(row+32)=perm+4
  const int perm0 =
      (((row0 >> 4) & 1) << 5) + ((row0 & 12) << 1) + (row0 & 3);
  const short* gK1b = K1p + (size_t)perm0 * 1024 + lc0 * 8;
  const short* gK2b = K2p + (size_t)perm0 * 1024 + lc0 * 8;
  const short* gV1b = V1p + (size_t)row0 * 2048 + lc0 * 8;
  const short* gV2b = V2p + (size_t)row0 * 2048 + lc0 * 8;
  short* dK1 = &K1s[0][cl0 * 8];
  short* dK2 = &K2s[0][cl0 * 8];
  short* dV1 = &V1s[0][cl0 * 8];
  short* dV2 = &V2s[0][cl0 * 8];

  // ---- fragment-read bases ----
  const int c0 = (g4 ^ (lrow & 7)) * 8;
  const int c1 = ((4 + g4) ^ (lrow & 7)) * 8;
  const int rb = lrow * 64;
  const short* rK1a = &K1s[0][rb + c0]; const short* rK1b = &K1s[0][rb + c1];
  const short* rK2a = &K2s[0][rb + c0]; const short* rK2b = &K2s[0][rb + c1];
  const short* rV1a = &V1s[0][rb + c0]; const short* rV1b = &V1s[0][rb + c1];
  const short* rV2a = &V2s[0][rb + c0]; const short* rV2b = &V2s[0][rb + c1];

#define STAGE(BUF, KT)                                                        \
  {                                                                           \
    gld_lds16(gK1b + (size_t)(KT) * 65536, dK1 + (BUF) * 4096);               \
    gld_lds16(gK1b + (size_t)(KT) * 65536 + 4096, dK1 + (BUF) * 4096 + 2048); \
    gld_lds16(gK2b + (size_t)(KT) * 65536, dK2 + (BUF) * 4096);               \
    gld_lds16(gK2b + (size_t)(KT) * 65536 + 4096, dK2 + (BUF) * 4096 + 2048); \
    gld_lds16(gV1b + (size_t)(KT) * 64, dV1 + (BUF) * 4096);                  \
    gld_lds16(gV1b + (size_t)(KT) * 64 + 65536, dV1 + (BUF) * 4096 + 2048);   \
    gld_lds16(gV2b + (size_t)(KT) * 64, dV2 + (BUF) * 4096);                  \
    gld_lds16(gV2b + (size_t)(KT) * 64 + 65536, dV2 + (BUF) * 4096 + 2048);   \
  }

// K fragments read ONCE, feed both q-groups (8 MFMA per nf)
#define QKSTEP(BUF, SA, SB)                                                   \
  {                                                                           \
    __builtin_amdgcn_s_setprio(1);                                            \
    _Pragma("unroll") for (int nf = 0; nf < 4; ++nf) {                        \
      bf16x8 k1a = *(const bf16x8*)(rK1a + (BUF)*4096 + nf * 1024);           \
      bf16x8 k1b = *(const bf16x8*)(rK1b + (BUF)*4096 + nf * 1024);           \
      bf16x8 k2a = *(const bf16x8*)(rK2a + (BUF)*4096 + nf * 1024);           \
      bf16x8 k2b = *(const bf16x8*)(rK2b + (BUF)*4096 + nf * 1024);           \
      SA[nf] = MFMA(k1a, q1A0, SA[nf]);                                       \
      SB[nf] = MFMA(k1a, q1B0, SB[nf]);                                       \
      SA[nf] = MFMA(k1b, q1A1, SA[nf]);                                       \
      SB[nf] = MFMA(k1b, q1B1, SB[nf]);                                       \
      SA[nf] = MFMA(k2a, q2A0, SA[nf]);                                       \
      SB[nf] = MFMA(k2a, q2B0, SB[nf]);                                       \
      SA[nf] = MFMA(k2b, q2A1, SA[nf]);                                       \
      SB[nf] = MFMA(k2b, q2B1, SB[nf]);                                       \
    }                                                                         \
    __builtin_amdgcn_s_setprio(0);                                            \
  }

#define PK2(a, b_) (__float22bfloat162_rn(float2{(a), (b_)}))

// online softmax for one group -> pb0/pb1 (P in PV B-fragment layout)
#define SM(S, MR, LR, O1, O2, PB0, PB1)                                       \
  {                                                                           \
    float mx = S[0][0];                                                       \
    _Pragma("unroll") for (int nf = 0; nf < 4; ++nf)                          \
        _Pragma("unroll") for (int r = 0; r < 4; ++r) mx =                    \
        fmaxf(mx, S[nf][r]);                                                  \
    if (!__all(mx - MR <= 8.0f)) {                                            \
      float rm = fmaxf(mx, __shfl_xor(mx, 16));                               \
      rm = fmaxf(rm, __shfl_xor(rm, 32));                                     \
      float newm = fmaxf(MR, rm);                                             \
      float corr = __expf(MR - newm);                                         \
      MR = newm;                                                              \
      LR *= corr;                                                             \
      _Pragma("unroll") for (int nf = 0; nf < 4; ++nf) {                      \
        O1[nf] *= corr;                                                       \
        O2[nf] *= corr;                                                       \
      }                                                                       \
    }                                                                         \
    float p[16];                                                              \
    _Pragma("unroll") for (int i = 0; i < 16; ++i) {                          \
      p[i] = __expf(S[i >> 2][i & 3] - MR);                                   \
      LR += p[i];                                                             \
    }                                                                         \
    __hip_bfloat162 h0 = PK2(p[0], p[1]), h1 = PK2(p[2], p[3]);               \
    __hip_bfloat162 h2 = PK2(p[8], p[9]), h3 = PK2(p[10], p[11]);             \
    __hip_bfloat162 h4 = PK2(p[4], p[5]), h5 = PK2(p[6], p[7]);               \
    __hip_bfloat162 h6 = PK2(p[12], p[13]), h7 = PK2(p[14], p[15]);           \
    i32x4 w0 = {*(int*)&h0, *(int*)&h1, *(int*)&h2, *(int*)&h3};              \
    i32x4 w1 = {*(int*)&h4, *(int*)&h5, *(int*)&h6, *(int*)&h7};              \
    PB0 = *(bf16x8*)&w0;                                                      \
    PB1 = *(bf16x8*)&w1;                                                      \
  }

// V fragments read ONCE, feed both q-groups (8 MFMA per nf)
#define PVSTEP(BUF, PA0, PA1, PB0, PB1)                                       \
  {                                                                           \
    __builtin_amdgcn_s_setprio(1);                                            \
    _Pragma("unroll") for (int nf = 0; nf < 4; ++nf) {                        \
      bf16x8 v1a = *(const bf16x8*)(rV1a + (BUF)*4096 + nf * 1024);           \
      bf16x8 v1b = *(const bf16x8*)(rV1b + (BUF)*4096 + nf * 1024);           \
      bf16x8 v2a = *(const bf16x8*)(rV2a + (BUF)*4096 + nf * 1024);           \
      bf16x8 v2b = *(const bf16x8*)(rV2b + (BUF)*4096 + nf * 1024);           \
      o1A[nf] = MFMA(v1a, PA0, o1A[nf]);                                      \
      o1B[nf] = MFMA(v1a, PB0, o1B[nf]);                                      \
      o1A[nf] = MFMA(v1b, PA1, o1A[nf]);                                      \
      o1B[nf] = MFMA(v1b, PB1, o1B[nf]);                                      \
      o2A[nf] = MFMA(v2a, PA0, o2A[nf]);                                      \
      o2B[nf] = MFMA(v2a, PB0, o2B[nf]);                                      \
      o2A[nf] = MFMA(v2b, PA1, o2A[nf]);                                      \
      o2B[nf] = MFMA(v2b, PB1, o2B[nf]);                                      \
    }                                                                         \
    __builtin_amdgcn_s_setprio(0);                                            \
  }

#define ITER(BUF)                                                             \
  {                                                                           \
    f32x4 sA[4] = {}, sB[4] = {};                                             \
    QKSTEP(BUF, sA, sB);                                                      \
    bf16x8 pA0, pA1, pB0, pB1;                                                \
    SM(sA, mrA, lrA, o1A, o2A, pA0, pA1);                                     \
    SM(sB, mrB, lrB, o1B, o2B, pB0, pB1);                                     \
    PVSTEP(BUF, pA0, pA1, pB0, pB1);                                          \
  }

  STAGE(0, 0);

  for (int tp = 0; tp < 16; ++tp) {
    // ---- even iter t=2tp, buffer 0 ----
    STAGE(1, 2 * tp + 1);
    asm volatile("s_waitcnt vmcnt(8)" ::: "memory");  // tile t landed
    __builtin_amdgcn_s_barrier();
    ITER(0);
    asm volatile("s_waitcnt lgkmcnt(0)" ::: "memory");
    __builtin_amdgcn_s_barrier();

    // ---- odd iter t=2tp+1, buffer 1 ----
    if (tp < 15) {
      STAGE(0, 2 * tp + 2);
      asm volatile("s_waitcnt vmcnt(8)" ::: "memory");
    } else {
      asm volatile("s_waitcnt vmcnt(0)" ::: "memory");
    }
    __builtin_amdgcn_s_barrier();
    ITER(1);
    asm volatile("s_waitcnt lgkmcnt(0)" ::: "memory");
    __builtin_amdgcn_s_barrier();
  }

  // epilogue: per-group lrun reduction + O^T writes [b, n, h*64+d]
#define EPI(LR, O1, O2, QROW)                                                 \
  {                                                                           \
    float lr = LR;                                                            \
    lr += __shfl_xor(lr, 16);                                                 \
    lr += __shfl_xor(lr, 32);                                                 \
    float inv = 1.0f / lr;                                                    \
    const size_t base1 = ((size_t)b * 4096 + (QROW)) * 512 + h * 64;          \
    const size_t base2 = base1 + (size_t)2048 * 512;                          \
    _Pragma("unroll") for (int nf = 0; nf < 4; ++nf) {                        \
      int d0 = nf * 16 + g4 * 4;                                              \
      s16x4 ov;                                                               \
      ov.x = f2bf(O1[nf][0] * inv);                                           \
      ov.y = f2bf(O1[nf][1] * inv);                                           \
      ov.z = f2bf(O1[nf][2] * inv);                                           \
      ov.w = f2bf(O1[nf][3] * inv);                                           \
      *(s16x4*)&Ocat[base1 + d0] = ov;                                        \
      ov.x = f2bf(O2[nf][0] * inv);                                           \
      ov.y = f2bf(O2[nf][1] * inv);                                           \
      ov.z = f2bf(O2[nf][2] * inv);                                           \
      ov.w = f2bf(O2[nf][3] * inv);                                           \
      *(s16x4*)&Ocat[base2 + d0] = ov;                                        \
    }                                                                         \
  }
  EPI(lrA, o1A, o2A, qrowA);
  EPI(lrB, o1B, o2B, qrowB);
}

// ---------------------------------------------------------------------------
extern "C" void kernel_launch(void* const* d_in, const int* in_sizes, int n_in,
                              void* d_out, int out_size, void* d_ws,
                              size_t ws_size, hipStream_t stream) {
  const float* x1 = (const float*)d_in[0];
  const float* x2 = (const float*)d_in[1];
  const float* Wq1 = (const float*)d_in[2];
  const float* Wq2 = (const float*)d_in[3];
  const float* Wo = (const float*)d_in[4];
  const float* bo = (const float*)d_in[5];
  float* out = (float*)d_out;

  // workspace layout (bf16 elements); total ~45.6 MB
  short* p = (short*)d_ws;
  short* xb1 = p;  p += (size_t)4096 * 512;
  short* xb2 = p;  p += (size_t)4096 * 512;
  short* W1t = p;  p += (size_t)1536 * 512;
  short* W2t = p;  p += (size_t)1536 * 512;
  short* Wot = p;  p += (size_t)512 * 512;
  short* QK1 = p;  p += (size_t)4096 * 1024;
  short* QK2 = p;  p += (size_t)4096 * 1024;
  short* Vt1 = p;  p += (size_t)2 * 8 * 64 * 2048;
  short* Vt2 = p;  p += (size_t)2 * 8 * 64 * 2048;
  short* Ocat = p; p += (size_t)8192 * 512;

  cast_bf16_dual<<<4096, 256, 0, stream>>>(x1, x2, xb1, xb2, 4096 * 512);
  cast_transpose3<<<7168, 256, 0, stream>>>(Wq1, Wq2, Wo, W1t, W2t, Wot);

  gemm_qkv<<<dim3(32, 24), 256, 0, stream>>>(xb1, xb2, W1t, W2t, QK1, QK2,
                                             Vt1, Vt2);

  attn_kernel<<<dim3(16, 16), 256, 0, stream>>>(QK1, QK2, Vt1, Vt2, Ocat);

  gemm_out<<<dim3(128, 4), 256, 0, stream>>>(Ocat, Wot, out, bo);
}

// Round 9
// 117.233 us; speedup vs baseline: 1.1282x; 1.1282x over previous
//
#include <hip/hip_runtime.h>
#include <hip/hip_bf16.h>

typedef __attribute__((ext_vector_type(8))) short bf16x8;
typedef __attribute__((ext_vector_type(4))) float f32x4;
typedef __attribute__((ext_vector_type(4))) short s16x4;
typedef __attribute__((ext_vector_type(4))) int i32x4;

#define MFMA(a, b, c) __builtin_amdgcn_mfma_f32_16x16x32_bf16(a, b, c, 0, 0, 0)

#define SCALE_F 0.08838834764831845f  // (2*64)^-0.5

__device__ __forceinline__ short f2bf(float f) {
  __hip_bfloat16 h = __float2bfloat16(f);
  return *reinterpret_cast<short*>(&h);
}

__device__ __forceinline__ void gld_lds16(const void* g, void* s) {
  __builtin_amdgcn_global_load_lds(
      (const __attribute__((address_space(1))) void*)g,
      (__attribute__((address_space(3))) void*)s, 16, 0, 0);
}

// ---------------------------------------------------------------------------
// cast fp32 -> bf16, two tensors in one launch
__global__ void cast_bf16_dual(const float* __restrict__ a,
                               const float* __restrict__ b,
                               short* __restrict__ oa, short* __restrict__ ob,
                               int n) {
  int idx = (blockIdx.x * 256 + threadIdx.x) * 4;
  const float* src = a;
  short* dst = oa;
  if (idx >= n) { idx -= n; src = b; dst = ob; }
  float4 v = *(const float4*)&src[idx];
  s16x4 o;
  o.x = f2bf(v.x); o.y = f2bf(v.y); o.z = f2bf(v.z); o.w = f2bf(v.w);
  *(s16x4*)&dst[idx] = o;
}

// merged transpose-cast of all three weights (R=512 for all):
// Wq1[512,1536]->W1t, Wq2->W2t (Q-cols pre-scaled), Wo[512,512]->Wot
__global__ void cast_transpose3(const float* __restrict__ Wq1,
                                const float* __restrict__ Wq2,
                                const float* __restrict__ Wo,
                                short* __restrict__ W1t,
                                short* __restrict__ W2t,
                                short* __restrict__ Wot) {
  int i = blockIdx.x * 256 + threadIdx.x;
  const float* src;
  short* dst;
  int C;
  if (i < 786432) {
    src = Wq1; dst = W1t; C = 1536;
  } else if (i < 1572864) {
    i -= 786432; src = Wq2; dst = W2t; C = 1536;
  } else {
    i -= 1572864;
    if (i >= 262144) return;
    src = Wo; dst = Wot; C = 512;
  }
  int r = i / C, c = i % C;
  float v = src[i];
  if (C == 1536 && c < 512) v *= SCALE_F;  // fold SCALE into Q block
  dst[(size_t)c * 512 + r] = f2bf(v);
}

// ---------------------------------------------------------------------------
// Merged dual-stream QKV GEMM: C = x @ Wqkv for both streams in one launch.
// grid (32, 24): blockIdx.y < 12 -> stream 1, else stream 2.
__global__ __launch_bounds__(256) void gemm_qkv(
    const short* __restrict__ xb1, const short* __restrict__ xb2,
    const short* __restrict__ W1t, const short* __restrict__ W2t,
    short* __restrict__ QK1, short* __restrict__ QK2,
    short* __restrict__ Vt1, short* __restrict__ Vt2) {
  __shared__ short As[128 * 64];
  __shared__ short Bs[128 * 64];
  const int tid = threadIdx.x;
  const int w = tid >> 6, l = tid & 63;
  const int sid = blockIdx.y >= 12;
  const short* A = sid ? xb2 : xb1;
  const short* Bt = sid ? W2t : W1t;
  short* C0 = sid ? QK2 : QK1;
  short* C1 = sid ? Vt2 : Vt1;
  const int m0 = blockIdx.x * 128;
  const int n0 = (sid ? blockIdx.y - 12 : blockIdx.y) * 128;
  const int mi = (w >> 1) * 64, ni = (w & 1) * 64;
  const int lrow = l & 15, lk8 = (l >> 4) * 8;
  const int K = 512;

  f32x4 acc[4][4] = {};

  for (int k0 = 0; k0 < K; k0 += 64) {
    for (int g = 0; g < 4; ++g) {
      int c = g * 256 + w * 64 + l;
      int row = c >> 3, c8 = (c & 7) * 8;
      int ldsoff = (g * 256 + w * 64) * 8;
      gld_lds16(A + (size_t)(m0 + row) * K + k0 + c8, (void*)(As + ldsoff));
      gld_lds16(Bt + (size_t)(n0 + row) * K + k0 + c8, (void*)(Bs + ldsoff));
    }
    __syncthreads();
    __builtin_amdgcn_s_setprio(1);
    for (int kp = 0; kp < 2; ++kp) {
      bf16x8 af[4], bfr[4];
      for (int mf = 0; mf < 4; ++mf)
        af[mf] = *(const bf16x8*)&As[(mi + mf * 16 + lrow) * 64 + kp * 32 + lk8];
      for (int nf = 0; nf < 4; ++nf)
        bfr[nf] = *(const bf16x8*)&Bs[(ni + nf * 16 + lrow) * 64 + kp * 32 + lk8];
      for (int mf = 0; mf < 4; ++mf)
        for (int nf = 0; nf < 4; ++nf)
          acc[mf][nf] = MFMA(af[mf], bfr[nf], acc[mf][nf]);
    }
    __builtin_amdgcn_s_setprio(0);
    __syncthreads();
  }

  for (int mf = 0; mf < 4; ++mf)
    for (int nf = 0; nf < 4; ++nf)
      for (int r = 0; r < 4; ++r) {
        int row = m0 + mi + mf * 16 + (l >> 4) * 4 + r;
        int col = n0 + ni + nf * 16 + lrow;
        float v = acc[mf][nf][r];
        if (col < 1024) {
          C0[(size_t)row * 1024 + col] = f2bf(v);
        } else {
          int b = row >> 11, n = row & 2047;
          int cv = col - 1024, h = cv >> 6, d = cv & 63;
          C1[(((size_t)(b * 8 + h) * 64 + d) << 11) + n] = f2bf(v);
        }
      }
}

// ---------------------------------------------------------------------------
// Output-projection GEMM, 64x128 tile (512 blocks -> 2 blocks/CU):
// Cf[8192,512] = A[8192,512] @ Wot[512,512]^T + bias
__global__ __launch_bounds__(256) void gemm_out(const short* __restrict__ A,
                                                const short* __restrict__ Bt,
                                                float* __restrict__ Cf,
                                                const float* __restrict__ bias) {
  __shared__ short As[64 * 64];
  __shared__ short Bs[128 * 64];
  const int tid = threadIdx.x;
  const int w = tid >> 6, l = tid & 63;
  const int m0 = blockIdx.x * 64, n0 = blockIdx.y * 128;
  const int mi = (w >> 1) * 32, ni = (w & 1) * 64;
  const int lrow = l & 15, lk8 = (l >> 4) * 8;
  const int K = 512, N = 512;

  f32x4 acc[2][4] = {};

  for (int k0 = 0; k0 < K; k0 += 64) {
    for (int g = 0; g < 2; ++g) {
      int c = g * 256 + tid;
      int row = c >> 3, c8 = (c & 7) * 8;
      gld_lds16(A + (size_t)(m0 + row) * K + k0 + c8, (void*)(As + c * 8));
    }
    for (int g = 0; g < 4; ++g) {
      int c = g * 256 + tid;
      int row = c >> 3, c8 = (c & 7) * 8;
      gld_lds16(Bt + (size_t)(n0 + row) * K + k0 + c8, (void*)(Bs + c * 8));
    }
    __syncthreads();
    __builtin_amdgcn_s_setprio(1);
    for (int kp = 0; kp < 2; ++kp) {
      bf16x8 af[2], bfr[4];
      for (int mf = 0; mf < 2; ++mf)
        af[mf] = *(const bf16x8*)&As[(mi + mf * 16 + lrow) * 64 + kp * 32 + lk8];
      for (int nf = 0; nf < 4; ++nf)
        bfr[nf] = *(const bf16x8*)&Bs[(ni + nf * 16 + lrow) * 64 + kp * 32 + lk8];
      for (int mf = 0; mf < 2; ++mf)
        for (int nf = 0; nf < 4; ++nf)
          acc[mf][nf] = MFMA(af[mf], bfr[nf], acc[mf][nf]);
    }
    __builtin_amdgcn_s_setprio(0);
    __syncthreads();
  }

  for (int mf = 0; mf < 2; ++mf)
    for (int nf = 0; nf < 4; ++nf)
      for (int r = 0; r < 4; ++r) {
        int row = m0 + mi + mf * 16 + (l >> 4) * 4 + r;
        int col = n0 + ni + nf * 16 + lrow;
        Cf[(size_t)row * N + col] = acc[mf][nf][r] + bias[col];
      }
}

// ---------------------------------------------------------------------------
// Dual-stream flash attention, v8: R6's proven per-wave structure scaled to
// 8 waves/block (512 threads, QBLK=128, grid(16,16)=256 blocks). LDS 64KB ->
// still 2 blocks/CU, but 16 waves/CU = 4 waves/SIMD (2x R6's TLP). Each
// thread stages ONE 16B chunk per array (4 gld_lds/stage -> vmcnt(4)).
// K/V HBM re-reads halve (16 q-blocks per bh instead of 32).
__global__ __launch_bounds__(512, 4) void attn_kernel(
    const short* __restrict__ QK1, const short* __restrict__ QK2,
    const short* __restrict__ Vt1, const short* __restrict__ Vt2,
    short* __restrict__ Ocat) {
  __shared__ short K1s[2][4096], K2s[2][4096], V1s[2][4096], V2s[2][4096];

  const int tid = threadIdx.x;
  const int w = tid >> 6, l = tid & 63;
  const int qb = blockIdx.x, bh = blockIdx.y;
  const int b = bh >> 3, h = bh & 7;
  const int lrow = l & 15, g4 = l >> 4, lk8 = g4 * 8;

  const short* Q1p = QK1 + (size_t)b * 2048 * 1024 + h * 64;
  const short* K1p = Q1p + 512;
  const short* Q2p = QK2 + (size_t)b * 2048 * 1024 + h * 64;
  const short* K2p = Q2p + 512;
  const short* V1p = Vt1 + (size_t)bh * 64 * 2048;
  const short* V2p = Vt2 + (size_t)bh * 64 * 2048;

  // Q fragments (B-operand: lane holds Q[q=lrow][d-chunk g4]) in registers
  const int qrow = qb * 128 + w * 16 + lrow;
  bf16x8 q1f[2], q2f[2];
  q1f[0] = *(const bf16x8*)&Q1p[(size_t)qrow * 1024 + lk8];
  q1f[1] = *(const bf16x8*)&Q1p[(size_t)qrow * 1024 + 32 + lk8];
  q2f[0] = *(const bf16x8*)&Q2p[(size_t)qrow * 1024 + lk8];
  q2f[1] = *(const bf16x8*)&Q2p[(size_t)qrow * 1024 + 32 + lk8];

  // O^T accumulators: o[nf][r] = O[d=nf*16+g4*4+r][q=lrow]
  f32x4 o1[4] = {}, o2[4] = {};
  float mrun = -1e30f, lrun = 0.f;

  // each of the 512 threads stages ONE 16B chunk per array
  auto stage = [&](int buf, int kt) {
    const int kv0 = kt * 64;
    int cl = tid;                   // LDS 16B-chunk index, linear 0..511
    int row = cl >> 3;
    int lc = (cl & 7) ^ (row & 7);  // bank-conflict XOR swizzle (rule 21)
    int ldsoff = cl * 8;
    // pi-permuted K row so the QK C-fragment lands in PV B-fragment layout
    int krow = kv0 + (((row >> 4) & 1) << 5) + ((row & 12) << 1) +
               ((row >> 5) << 2) + (row & 3);
    gld_lds16(K1p + (size_t)krow * 1024 + lc * 8, (void*)(&K1s[buf][ldsoff]));
    gld_lds16(K2p + (size_t)krow * 1024 + lc * 8, (void*)(&K2s[buf][ldsoff]));
    gld_lds16(V1p + (size_t)row * 2048 + kv0 + lc * 8, (void*)(&V1s[buf][ldsoff]));
    gld_lds16(V2p + (size_t)row * 2048 + kv0 + lc * 8, (void*)(&V2s[buf][ldsoff]));
  };
  auto sw = [&](int row, int kc) { return row * 64 + ((kc ^ (row & 7)) * 8); };

  int cur = 0;
  stage(0, 0);

  for (int kt = 0; kt < 32; ++kt) {
    if (kt + 1 < 32) {
      stage(cur ^ 1, kt + 1);  // 4 loads in flight across the whole iter
      asm volatile("s_waitcnt vmcnt(4)" ::: "memory");  // tile t complete
    } else {
      asm volatile("s_waitcnt vmcnt(0)" ::: "memory");  // last tile: drain
    }
    __builtin_amdgcn_s_barrier();  // tile t published to all waves

    // S^T (pre-scaled): lane (g4,lrow) gets kv = 32*(nf&1)+8*g4+4*(nf>>1)+r
    f32x4 s[4] = {};
    __builtin_amdgcn_s_setprio(1);
#pragma unroll
    for (int nf = 0; nf < 4; ++nf) {
      int row = nf * 16 + lrow;
      bf16x8 k1a = *(const bf16x8*)&K1s[cur][sw(row, g4)];
      bf16x8 k1b = *(const bf16x8*)&K1s[cur][sw(row, 4 + g4)];
      bf16x8 k2a = *(const bf16x8*)&K2s[cur][sw(row, g4)];
      bf16x8 k2b = *(const bf16x8*)&K2s[cur][sw(row, 4 + g4)];
      s[nf] = MFMA(k1a, q1f[0], s[nf]);
      s[nf] = MFMA(k1b, q1f[1], s[nf]);
      s[nf] = MFMA(k2a, q2f[0], s[nf]);
      s[nf] = MFMA(k2b, q2f[1], s[nf]);
    }
    __builtin_amdgcn_s_setprio(0);

    // online softmax, zero cross-lane ops in the common path
    float t[16];
#pragma unroll
    for (int nf = 0; nf < 4; ++nf)
#pragma unroll
      for (int r = 0; r < 4; ++r) t[nf * 4 + r] = s[nf][r];
    float mx = t[0];
#pragma unroll
    for (int i = 1; i < 16; ++i) mx = fmaxf(mx, t[i]);
    if (!__all(mx - mrun <= 8.0f)) {  // wave-AND doubles as the max reduce
      float rm = fmaxf(mx, __shfl_xor(mx, 16));
      rm = fmaxf(rm, __shfl_xor(rm, 32));
      float newm = fmaxf(mrun, rm);
      float corr = __expf(mrun - newm);
      mrun = newm;
      lrun *= corr;  // lrun is per-lane partial; corr is row-uniform
#pragma unroll
      for (int nf = 0; nf < 4; ++nf)
#pragma unroll
        for (int r = 0; r < 4; ++r) { o1[nf][r] *= corr; o2[nf][r] *= corr; }
    }
    float p[16];
#pragma unroll
    for (int i = 0; i < 16; ++i) { p[i] = __expf(t[i] - mrun); lrun += p[i]; }

    // P already lane-resident in PV B-layout: pb0=[s0|s2], pb1=[s1|s3]
    bf16x8 pb0, pb1;
#pragma unroll
    for (int j = 0; j < 4; ++j) {
      pb0[j] = f2bf(p[j]);
      pb0[4 + j] = f2bf(p[8 + j]);
      pb1[j] = f2bf(p[4 + j]);
      pb1[4 + j] = f2bf(p[12 + j]);
    }

    // PV: O^T += V^T P^T
    __builtin_amdgcn_s_setprio(1);
#pragma unroll
    for (int nf = 0; nf < 4; ++nf) {
      int row = nf * 16 + lrow;
      bf16x8 v1a = *(const bf16x8*)&V1s[cur][sw(row, g4)];
      bf16x8 v1b = *(const bf16x8*)&V1s[cur][sw(row, 4 + g4)];
      bf16x8 v2a = *(const bf16x8*)&V2s[cur][sw(row, g4)];
      bf16x8 v2b = *(const bf16x8*)&V2s[cur][sw(row, 4 + g4)];
      o1[nf] = MFMA(v1a, pb0, o1[nf]);
      o1[nf] = MFMA(v1b, pb1, o1[nf]);
      o2[nf] = MFMA(v2a, pb0, o2[nf]);
      o2[nf] = MFMA(v2b, pb1, o2[nf]);
    }
    __builtin_amdgcn_s_setprio(0);

    // all my LDS reads of buf `cur` done -> publish, then next iter may
    // overwrite it with stage(t+2)
    asm volatile("s_waitcnt lgkmcnt(0)" ::: "memory");
    __builtin_amdgcn_s_barrier();
    cur ^= 1;
  }

  // epilogue: reduce per-lane partial lrun across the 4 g4-lanes of the row
  lrun += __shfl_xor(lrun, 16);
  lrun += __shfl_xor(lrun, 32);
  float inv = 1.0f / lrun;
  const size_t base1 = ((size_t)b * 4096 + qrow) * 512 + h * 64;
  const size_t base2 = base1 + (size_t)2048 * 512;
#pragma unroll
  for (int nf = 0; nf < 4; ++nf) {
    int d0 = nf * 16 + g4 * 4;
    s16x4 ov;
    ov.x = f2bf(o1[nf][0] * inv);
    ov.y = f2bf(o1[nf][1] * inv);
    ov.z = f2bf(o1[nf][2] * inv);
    ov.w = f2bf(o1[nf][3] * inv);
    *(s16x4*)&Ocat[base1 + d0] = ov;
    ov.x = f2bf(o2[nf][0] * inv);
    ov.y = f2bf(o2[nf][1] * inv);
    ov.z = f2bf(o2[nf][2] * inv);
    ov.w = f2bf(o2[nf][3] * inv);
    *(s16x4*)&Ocat[base2 + d0] = ov;
  }
}

// ---------------------------------------------------------------------------
extern "C" void kernel_launch(void* const* d_in, const int* in_sizes, int n_in,
                              void* d_out, int out_size, void* d_ws,
                              size_t ws_size, hipStream_t stream) {
  const float* x1 = (const float*)d_in[0];
  const float* x2 = (const float*)d_in[1];
  const float* Wq1 = (const float*)d_in[2];
  const float* Wq2 = (const float*)d_in[3];
  const float* Wo = (const float*)d_in[4];
  const float* bo = (const float*)d_in[5];
  float* out = (float*)d_out;

  // workspace layout (bf16 elements); total ~45.6 MB
  short* p = (short*)d_ws;
  short* xb1 = p;  p += (size_t)4096 * 512;
  short* xb2 = p;  p += (size_t)4096 * 512;
  short* W1t = p;  p += (size_t)1536 * 512;
  short* W2t = p;  p += (size_t)1536 * 512;
  short* Wot = p;  p += (size_t)512 * 512;
  short* QK1 = p;  p += (size_t)4096 * 1024;
  short* QK2 = p;  p += (size_t)4096 * 1024;
  short* Vt1 = p;  p += (size_t)2 * 8 * 64 * 2048;
  short* Vt2 = p;  p += (size_t)2 * 8 * 64 * 2048;
  short* Ocat = p; p += (size_t)8192 * 512;

  cast_bf16_dual<<<4096, 256, 0, stream>>>(x1, x2, xb1, xb2, 4096 * 512);
  cast_transpose3<<<7168, 256, 0, stream>>>(Wq1, Wq2, Wo, W1t, W2t, Wot);

  gemm_qkv<<<dim3(32, 24), 256, 0, stream>>>(xb1, xb2, W1t, W2t, QK1, QK2,
                                             Vt1, Vt2);

  attn_kernel<<<dim3(16, 16), 512, 0, stream>>>(QK1, QK2, Vt1, Vt2, Ocat);

  gemm_out<<<dim3(128, 4), 256, 0, stream>>>(Ocat, Wot, out, bo);
}

// Round 10
// 109.804 us; speedup vs baseline: 1.2045x; 1.0677x over previous
//
#include <hip/hip_runtime.h>
#include <hip/hip_bf16.h>

typedef __attribute__((ext_vector_type(8))) short bf16x8;
typedef __attribute__((ext_vector_type(4))) float f32x4;
typedef __attribute__((ext_vector_type(16))) float f32x16;
typedef __attribute__((ext_vector_type(4))) short s16x4;
typedef __attribute__((ext_vector_type(4))) int i32x4;

#define MFMA(a, b, c) __builtin_amdgcn_mfma_f32_16x16x32_bf16(a, b, c, 0, 0, 0)
#define MFMA32(a, b, c) __builtin_amdgcn_mfma_f32_32x32x16_bf16(a, b, c, 0, 0, 0)

#define SCALE_F 0.08838834764831845f  // (2*64)^-0.5

__device__ __forceinline__ short f2bf(float f) {
  __hip_bfloat16 h = __float2bfloat16(f);
  return *reinterpret_cast<short*>(&h);
}

__device__ __forceinline__ void gld_lds16(const void* g, void* s) {
  __builtin_amdgcn_global_load_lds(
      (const __attribute__((address_space(1))) void*)g,
      (__attribute__((address_space(3))) void*)s, 16, 0, 0);
}

// ---------------------------------------------------------------------------
// cast fp32 -> bf16, two tensors in one launch
__global__ void cast_bf16_dual(const float* __restrict__ a,
                               const float* __restrict__ b,
                               short* __restrict__ oa, short* __restrict__ ob,
                               int n) {
  int idx = (blockIdx.x * 256 + threadIdx.x) * 4;
  const float* src = a;
  short* dst = oa;
  if (idx >= n) { idx -= n; src = b; dst = ob; }
  float4 v = *(const float4*)&src[idx];
  s16x4 o;
  o.x = f2bf(v.x); o.y = f2bf(v.y); o.z = f2bf(v.z); o.w = f2bf(v.w);
  *(s16x4*)&dst[idx] = o;
}

// merged transpose-cast of all three weights (R=512 for all):
// Wq1[512,1536]->W1t, Wq2->W2t (Q-cols pre-scaled), Wo[512,512]->Wot
__global__ void cast_transpose3(const float* __restrict__ Wq1,
                                const float* __restrict__ Wq2,
                                const float* __restrict__ Wo,
                                short* __restrict__ W1t,
                                short* __restrict__ W2t,
                                short* __restrict__ Wot) {
  int i = blockIdx.x * 256 + threadIdx.x;
  const float* src;
  short* dst;
  int C;
  if (i < 786432) {
    src = Wq1; dst = W1t; C = 1536;
  } else if (i < 1572864) {
    i -= 786432; src = Wq2; dst = W2t; C = 1536;
  } else {
    i -= 1572864;
    if (i >= 262144) return;
    src = Wo; dst = Wot; C = 512;
  }
  int r = i / C, c = i % C;
  float v = src[i];
  if (C == 1536 && c < 512) v *= SCALE_F;  // fold SCALE into Q block
  dst[(size_t)c * 512 + r] = f2bf(v);
}

// ---------------------------------------------------------------------------
// Merged dual-stream QKV GEMM: C = x @ Wqkv for both streams in one launch.
// grid (32, 24): blockIdx.y < 12 -> stream 1, else stream 2.
__global__ __launch_bounds__(256) void gemm_qkv(
    const short* __restrict__ xb1, const short* __restrict__ xb2,
    const short* __restrict__ W1t, const short* __restrict__ W2t,
    short* __restrict__ QK1, short* __restrict__ QK2,
    short* __restrict__ Vt1, short* __restrict__ Vt2) {
  __shared__ short As[128 * 64];
  __shared__ short Bs[128 * 64];
  const int tid = threadIdx.x;
  const int w = tid >> 6, l = tid & 63;
  const int sid = blockIdx.y >= 12;
  const short* A = sid ? xb2 : xb1;
  const short* Bt = sid ? W2t : W1t;
  short* C0 = sid ? QK2 : QK1;
  short* C1 = sid ? Vt2 : Vt1;
  const int m0 = blockIdx.x * 128;
  const int n0 = (sid ? blockIdx.y - 12 : blockIdx.y) * 128;
  const int mi = (w >> 1) * 64, ni = (w & 1) * 64;
  const int lrow = l & 15, lk8 = (l >> 4) * 8;
  const int K = 512;

  f32x4 acc[4][4] = {};

  for (int k0 = 0; k0 < K; k0 += 64) {
    for (int g = 0; g < 4; ++g) {
      int c = g * 256 + w * 64 + l;
      int row = c >> 3, c8 = (c & 7) * 8;
      int ldsoff = (g * 256 + w * 64) * 8;
      gld_lds16(A + (size_t)(m0 + row) * K + k0 + c8, (void*)(As + ldsoff));
      gld_lds16(Bt + (size_t)(n0 + row) * K + k0 + c8, (void*)(Bs + ldsoff));
    }
    __syncthreads();
    __builtin_amdgcn_s_setprio(1);
    for (int kp = 0; kp < 2; ++kp) {
      bf16x8 af[4], bfr[4];
      for (int mf = 0; mf < 4; ++mf)
        af[mf] = *(const bf16x8*)&As[(mi + mf * 16 + lrow) * 64 + kp * 32 + lk8];
      for (int nf = 0; nf < 4; ++nf)
        bfr[nf] = *(const bf16x8*)&Bs[(ni + nf * 16 + lrow) * 64 + kp * 32 + lk8];
      for (int mf = 0; mf < 4; ++mf)
        for (int nf = 0; nf < 4; ++nf)
          acc[mf][nf] = MFMA(af[mf], bfr[nf], acc[mf][nf]);
    }
    __builtin_amdgcn_s_setprio(0);
    __syncthreads();
  }

  for (int mf = 0; mf < 4; ++mf)
    for (int nf = 0; nf < 4; ++nf)
      for (int r = 0; r < 4; ++r) {
        int row = m0 + mi + mf * 16 + (l >> 4) * 4 + r;
        int col = n0 + ni + nf * 16 + lrow;
        float v = acc[mf][nf][r];
        if (col < 1024) {
          C0[(size_t)row * 1024 + col] = f2bf(v);
        } else {
          int b = row >> 11, n = row & 2047;
          int cv = col - 1024, h = cv >> 6, d = cv & 63;
          C1[(((size_t)(b * 8 + h) * 64 + d) << 11) + n] = f2bf(v);
        }
      }
}

// ---------------------------------------------------------------------------
// Output-projection GEMM, 64x128 tile (512 blocks -> 2 blocks/CU):
// Cf[8192,512] = A[8192,512] @ Wot[512,512]^T + bias
__global__ __launch_bounds__(256) void gemm_out(const short* __restrict__ A,
                                                const short* __restrict__ Bt,
                                                float* __restrict__ Cf,
                                                const float* __restrict__ bias) {
  __shared__ short As[64 * 64];
  __shared__ short Bs[128 * 64];
  const int tid = threadIdx.x;
  const int w = tid >> 6, l = tid & 63;
  const int m0 = blockIdx.x * 64, n0 = blockIdx.y * 128;
  const int mi = (w >> 1) * 32, ni = (w & 1) * 64;
  const int lrow = l & 15, lk8 = (l >> 4) * 8;
  const int K = 512, N = 512;

  f32x4 acc[2][4] = {};

  for (int k0 = 0; k0 < K; k0 += 64) {
    for (int g = 0; g < 2; ++g) {
      int c = g * 256 + tid;
      int row = c >> 3, c8 = (c & 7) * 8;
      gld_lds16(A + (size_t)(m0 + row) * K + k0 + c8, (void*)(As + c * 8));
    }
    for (int g = 0; g < 4; ++g) {
      int c = g * 256 + tid;
      int row = c >> 3, c8 = (c & 7) * 8;
      gld_lds16(Bt + (size_t)(n0 + row) * K + k0 + c8, (void*)(Bs + c * 8));
    }
    __syncthreads();
    __builtin_amdgcn_s_setprio(1);
    for (int kp = 0; kp < 2; ++kp) {
      bf16x8 af[2], bfr[4];
      for (int mf = 0; mf < 2; ++mf)
        af[mf] = *(const bf16x8*)&As[(mi + mf * 16 + lrow) * 64 + kp * 32 + lk8];
      for (int nf = 0; nf < 4; ++nf)
        bfr[nf] = *(const bf16x8*)&Bs[(ni + nf * 16 + lrow) * 64 + kp * 32 + lk8];
      for (int mf = 0; mf < 2; ++mf)
        for (int nf = 0; nf < 4; ++nf)
          acc[mf][nf] = MFMA(af[mf], bfr[nf], acc[mf][nf]);
    }
    __builtin_amdgcn_s_setprio(0);
    __syncthreads();
  }

  for (int mf = 0; mf < 2; ++mf)
    for (int nf = 0; nf < 4; ++nf)
      for (int r = 0; r < 4; ++r) {
        int row = m0 + mi + mf * 16 + (l >> 4) * 4 + r;
        int col = n0 + ni + nf * 16 + lrow;
        Cf[(size_t)row * N + col] = acc[mf][nf][r] + bias[col];
      }
}

// ---------------------------------------------------------------------------
// Dual-stream flash attention, v9: mfma_32x32x16 (halves LDS bytes/FLOP).
// Block = 4 waves = 2 q-groups (wq, 32 q each) x 2 kv-halves (wk). Wave
// handles 32 q x 32 kv per 64-kv tile -> 16 ds_read_b128 + 16 MFMA/tile.
// kv-partition across wk: independent online-softmax (m,l,O) per wave over
// its kv subset; exact merge at the end: O = sum O_w * exp(m_w - m*).
// K staged per 32-row half with pi(lr)=16*u0+8*hi+4*u1+v (u=lr>>3 bits,
// hi=(lr>>2)&1, v=lr&3) so the S^T C-fragment IS the PV B-fragment:
// pb0 = s regs{0-3,8-11}, pb1 = {4-7,12-15}. XOR bank swizzle as before.
__global__ __launch_bounds__(256, 2) void attn_kernel(
    const short* __restrict__ QK1, const short* __restrict__ QK2,
    const short* __restrict__ Vt1, const short* __restrict__ Vt2,
    short* __restrict__ Ocat) {
  __shared__ short lds[32768];  // 64KB: K1[2][4096] K2 V1 V2 (shorts)
  short* K1s = lds;
  short* K2s = lds + 8192;
  short* V1s = lds + 16384;
  short* V2s = lds + 24576;

  const int tid = threadIdx.x;
  const int w = tid >> 6, l = tid & 63;
  const int wq = w & 1, wk = w >> 1;
  const int lq = l & 31, hi = l >> 5;
  const int qb = blockIdx.x, bh = blockIdx.y;
  const int b = bh >> 3, h = bh & 7;

  const short* Q1p = QK1 + (size_t)b * 2048 * 1024 + h * 64;
  const short* K1p = Q1p + 512;
  const short* Q2p = QK2 + (size_t)b * 2048 * 1024 + h * 64;
  const short* K2p = Q2p + 512;
  const short* V1p = Vt1 + (size_t)bh * 64 * 2048;
  const short* V2p = Vt2 + (size_t)bh * 64 * 2048;

  // Q fragments: lane holds Q[q=lq][d = 16*ck + 8*hi + j], j=0..8
  const int qrow = qb * 64 + wq * 32 + lq;
  bf16x8 q1f[4], q2f[4];
#pragma unroll
  for (int ck = 0; ck < 4; ++ck) {
    q1f[ck] = *(const bf16x8*)&Q1p[(size_t)qrow * 1024 + ck * 16 + hi * 8];
    q2f[ck] = *(const bf16x8*)&Q2p[(size_t)qrow * 1024 + ck * 16 + hi * 8];
  }

  // O^T accumulators: o*a = d 0..31 tile, o*b = d 32..63; col = q = lq
  f32x16 o1a = {}, o1b = {}, o2a = {}, o2b = {};
  float mrun = -1e30f, lrun = 0.f;

  auto stage = [&](int buf, int kt) {
    const int kv0 = kt * 64;
#pragma unroll
    for (int gg = 0; gg < 2; ++gg) {
      int cl = gg * 256 + tid;
      int row = cl >> 3;
      int lc = (cl & 7) ^ (row & 7);  // bank-conflict XOR swizzle (rule 21)
      int lr = row & 31;
      // pi-permuted K row within each 32-row half
      int krow = kv0 + ((row >> 5) << 5) + (((lr >> 3) & 1) << 4) +
                 (((lr >> 2) & 1) << 3) + (((lr >> 4) & 1) << 2) + (lr & 3);
      int doff = buf * 4096 + cl * 8;
      gld_lds16(K1p + (size_t)krow * 1024 + lc * 8, (void*)(K1s + doff));
      gld_lds16(K2p + (size_t)krow * 1024 + lc * 8, (void*)(K2s + doff));
      gld_lds16(V1p + (size_t)row * 2048 + kv0 + lc * 8, (void*)(V1s + doff));
      gld_lds16(V2p + (size_t)row * 2048 + kv0 + lc * 8, (void*)(V2s + doff));
    }
  };
  auto swo = [&](int row, int kc) { return row * 64 + ((kc ^ (row & 7)) * 8); };

  int cur = 0;
  stage(0, 0);

  for (int kt = 0; kt < 32; ++kt) {
    if (kt + 1 < 32) {
      stage(cur ^ 1, kt + 1);  // 8 loads stay in flight across the iter
      asm volatile("s_waitcnt vmcnt(8)" ::: "memory");  // tile t complete
    } else {
      asm volatile("s_waitcnt vmcnt(0)" ::: "memory");
    }
    __builtin_amdgcn_s_barrier();

    // S^T[32 kv][32 q] for this wave's kv-half, both streams accumulated
    const int krd = 32 * wk + lq;
    f32x16 s = {};
    __builtin_amdgcn_s_setprio(1);
#pragma unroll
    for (int ck = 0; ck < 4; ++ck) {
      bf16x8 k1 = *(const bf16x8*)&K1s[cur * 4096 + swo(krd, 2 * ck + hi)];
      bf16x8 k2 = *(const bf16x8*)&K2s[cur * 4096 + swo(krd, 2 * ck + hi)];
      s = MFMA32(k1, q1f[ck], s);
      s = MFMA32(k2, q2f[ck], s);
    }
    __builtin_amdgcn_s_setprio(0);

    // online softmax over lane's 16 kv values (partner l^32 has other 16)
    float mx = s[0];
#pragma unroll
    for (int i = 1; i < 16; ++i) mx = fmaxf(mx, s[i]);
    if (!__all(mx - mrun <= 8.0f)) {  // defer-max: rarely fires
      float rm = fmaxf(mx, __shfl_xor(mx, 32));
      float newm = fmaxf(mrun, rm);
      float corr = __expf(mrun - newm);
      mrun = newm;
      lrun *= corr;
#pragma unroll
      for (int i = 0; i < 16; ++i) {
        o1a[i] *= corr; o1b[i] *= corr; o2a[i] *= corr; o2b[i] *= corr;
      }
    }
    float p[16];
#pragma unroll
    for (int i = 0; i < 16; ++i) { p[i] = __expf(s[i] - mrun); lrun += p[i]; }

    // P register-local repack: pb[c][j] = p[(j&3) + 4c + 8*(j>>2)]
    __hip_bfloat162 a0 = __float22bfloat162_rn(float2{p[0], p[1]});
    __hip_bfloat162 a1 = __float22bfloat162_rn(float2{p[2], p[3]});
    __hip_bfloat162 a2 = __float22bfloat162_rn(float2{p[8], p[9]});
    __hip_bfloat162 a3 = __float22bfloat162_rn(float2{p[10], p[11]});
    __hip_bfloat162 b0 = __float22bfloat162_rn(float2{p[4], p[5]});
    __hip_bfloat162 b1 = __float22bfloat162_rn(float2{p[6], p[7]});
    __hip_bfloat162 b2 = __float22bfloat162_rn(float2{p[12], p[13]});
    __hip_bfloat162 b3 = __float22bfloat162_rn(float2{p[14], p[15]});
    i32x4 w0 = {*(int*)&a0, *(int*)&a1, *(int*)&a2, *(int*)&a3};
    i32x4 w1 = {*(int*)&b0, *(int*)&b1, *(int*)&b2, *(int*)&b3};
    bf16x8 pb0 = *(bf16x8*)&w0, pb1 = *(bf16x8*)&w1;

    // PV: O^T += V^T P^T over this wave's kv-half
    __builtin_amdgcn_s_setprio(1);
#pragma unroll
    for (int c = 0; c < 2; ++c) {
      bf16x8 pb = c ? pb1 : pb0;
      int kcv = 4 * wk + 2 * c + hi;
      bf16x8 v1a = *(const bf16x8*)&V1s[cur * 4096 + swo(lq, kcv)];
      bf16x8 v1b = *(const bf16x8*)&V1s[cur * 4096 + swo(32 + lq, kcv)];
      bf16x8 v2a = *(const bf16x8*)&V2s[cur * 4096 + swo(lq, kcv)];
      bf16x8 v2b = *(const bf16x8*)&V2s[cur * 4096 + swo(32 + lq, kcv)];
      o1a = MFMA32(v1a, pb, o1a);
      o1b = MFMA32(v1b, pb, o1b);
      o2a = MFMA32(v2a, pb, o2a);
      o2b = MFMA32(v2b, pb, o2b);
    }
    __builtin_amdgcn_s_setprio(0);

    asm volatile("s_waitcnt lgkmcnt(0)" ::: "memory");
    __builtin_amdgcn_s_barrier();
    cur ^= 1;
  }

  // ---- cross-wk merge: exact combine of the two kv-half partials ----
  lrun += __shfl_xor(lrun, 32);  // per-q total for this wave's half
  float* cb = (float*)lds;
  float* rg = cb + wq * 4224;  // per-wq region: 4096 O + 64 m + 64 l floats
  if (wk == 1) {
#pragma unroll
    for (int i = 0; i < 16; ++i) {
      rg[i * 64 + l] = o1a[i];
      rg[(16 + i) * 64 + l] = o1b[i];
      rg[(32 + i) * 64 + l] = o2a[i];
      rg[(48 + i) * 64 + l] = o2b[i];
    }
    rg[4096 + l] = mrun;
    rg[4160 + l] = lrun;
  }
  __syncthreads();
  if (wk == 0) {
    float m1 = rg[4096 + l], l1 = rg[4160 + l];
    float mstar = fmaxf(mrun, m1);
    float e0 = __expf(mrun - mstar), e1 = __expf(m1 - mstar);
    float inv = 1.0f / (lrun * e0 + l1 * e1);
    float av0 = e0 * inv, av1 = e1 * inv;
#pragma unroll
    for (int i = 0; i < 16; ++i) {
      o1a[i] = o1a[i] * av0 + rg[i * 64 + l] * av1;
      o1b[i] = o1b[i] * av0 + rg[(16 + i) * 64 + l] * av1;
      o2a[i] = o2a[i] * av0 + rg[(32 + i) * 64 + l] * av1;
      o2b[i] = o2b[i] * av0 + rg[(48 + i) * 64 + l] * av1;
    }
    // write: lane's d rows = 8*rq + 4*hi + e (+32 for *b tiles), q = lq
    const size_t base1 = ((size_t)b * 4096 + qrow) * 512 + h * 64;
    const size_t base2 = base1 + (size_t)2048 * 512;
#pragma unroll
    for (int rq = 0; rq < 4; ++rq) {
      int d0 = 8 * rq + 4 * hi;
      s16x4 ov;
      ov.x = f2bf(o1a[rq * 4 + 0]); ov.y = f2bf(o1a[rq * 4 + 1]);
      ov.z = f2bf(o1a[rq * 4 + 2]); ov.w = f2bf(o1a[rq * 4 + 3]);
      *(s16x4*)&Ocat[base1 + d0] = ov;
      ov.x = f2bf(o1b[rq * 4 + 0]); ov.y = f2bf(o1b[rq * 4 + 1]);
      ov.z = f2bf(o1b[rq * 4 + 2]); ov.w = f2bf(o1b[rq * 4 + 3]);
      *(s16x4*)&Ocat[base1 + 32 + d0] = ov;
      ov.x = f2bf(o2a[rq * 4 + 0]); ov.y = f2bf(o2a[rq * 4 + 1]);
      ov.z = f2bf(o2a[rq * 4 + 2]); ov.w = f2bf(o2a[rq * 4 + 3]);
      *(s16x4*)&Ocat[base2 + d0] = ov;
      ov.x = f2bf(o2b[rq * 4 + 0]); ov.y = f2bf(o2b[rq * 4 + 1]);
      ov.z = f2bf(o2b[rq * 4 + 2]); ov.w = f2bf(o2b[rq * 4 + 3]);
      *(s16x4*)&Ocat[base2 + 32 + d0] = ov;
    }
  }
}

// ---------------------------------------------------------------------------
extern "C" void kernel_launch(void* const* d_in, const int* in_sizes, int n_in,
                              void* d_out, int out_size, void* d_ws,
                              size_t ws_size, hipStream_t stream) {
  const float* x1 = (const float*)d_in[0];
  const float* x2 = (const float*)d_in[1];
  const float* Wq1 = (const float*)d_in[2];
  const float* Wq2 = (const float*)d_in[3];
  const float* Wo = (const float*)d_in[4];
  const float* bo = (const float*)d_in[5];
  float* out = (float*)d_out;

  // workspace layout (bf16 elements); total ~45.6 MB
  short* p = (short*)d_ws;
  short* xb1 = p;  p += (size_t)4096 * 512;
  short* xb2 = p;  p += (size_t)4096 * 512;
  short* W1t = p;  p += (size_t)1536 * 512;
  short* W2t = p;  p += (size_t)1536 * 512;
  short* Wot = p;  p += (size_t)512 * 512;
  short* QK1 = p;  p += (size_t)4096 * 1024;
  short* QK2 = p;  p += (size_t)4096 * 1024;
  short* Vt1 = p;  p += (size_t)2 * 8 * 64 * 2048;
  short* Vt2 = p;  p += (size_t)2 * 8 * 64 * 2048;
  short* Ocat = p; p += (size_t)8192 * 512;

  cast_bf16_dual<<<4096, 256, 0, stream>>>(x1, x2, xb1, xb2, 4096 * 512);
  cast_transpose3<<<7168, 256, 0, stream>>>(Wq1, Wq2, Wo, W1t, W2t, Wot);

  gemm_qkv<<<dim3(32, 24), 256, 0, stream>>>(xb1, xb2, W1t, W2t, QK1, QK2,
                                             Vt1, Vt2);

  attn_kernel<<<dim3(32, 16), 256, 0, stream>>>(QK1, QK2, Vt1, Vt2, Ocat);

  gemm_out<<<dim3(128, 4), 256, 0, stream>>>(Ocat, Wot, out, bo);
}

// Round 11
// 102.319 us; speedup vs baseline: 1.2926x; 1.0731x over previous
//
#include <hip/hip_runtime.h>
#include <hip/hip_bf16.h>

typedef __attribute__((ext_vector_type(8))) short bf16x8;
typedef __attribute__((ext_vector_type(4))) float f32x4;
typedef __attribute__((ext_vector_type(16))) float f32x16;
typedef __attribute__((ext_vector_type(4))) short s16x4;
typedef __attribute__((ext_vector_type(4))) int i32x4;

#define MFMA(a, b, c) __builtin_amdgcn_mfma_f32_16x16x32_bf16(a, b, c, 0, 0, 0)
#define MFMA32(a, b, c) __builtin_amdgcn_mfma_f32_32x32x16_bf16(a, b, c, 0, 0, 0)

#define SCALE_F 0.08838834764831845f  // (2*64)^-0.5

__device__ __forceinline__ short f2bf(float f) {
  __hip_bfloat16 h = __float2bfloat16(f);
  return *reinterpret_cast<short*>(&h);
}

__device__ __forceinline__ void gld_lds16(const void* g, void* s) {
  __builtin_amdgcn_global_load_lds(
      (const __attribute__((address_space(1))) void*)g,
      (__attribute__((address_space(3))) void*)s, 16, 0, 0);
}

// ---------------------------------------------------------------------------
// cast fp32 -> bf16, two tensors in one launch
__global__ void cast_bf16_dual(const float* __restrict__ a,
                               const float* __restrict__ b,
                               short* __restrict__ oa, short* __restrict__ ob,
                               int n) {
  int idx = (blockIdx.x * 256 + threadIdx.x) * 4;
  const float* src = a;
  short* dst = oa;
  if (idx >= n) { idx -= n; src = b; dst = ob; }
  float4 v = *(const float4*)&src[idx];
  s16x4 o;
  o.x = f2bf(v.x); o.y = f2bf(v.y); o.z = f2bf(v.z); o.w = f2bf(v.w);
  *(s16x4*)&dst[idx] = o;
}

// LDS-tiled transpose-cast of the three weights (64x64 f32 tiles, coalesced
// reads AND writes; the old version scattered 2B stores at 1KB stride).
// Wq1: tiles 0..191 (8x24), Wq2: 192..383, Wo: 384..447 (8x8).
__global__ __launch_bounds__(256) void cast_transpose_tiled(
    const float* __restrict__ Wq1, const float* __restrict__ Wq2,
    const float* __restrict__ Wo, short* __restrict__ W1t,
    short* __restrict__ W2t, short* __restrict__ Wot) {
  __shared__ float t[64][65];  // +1 pad: conflict-free column reads
  int bid = blockIdx.x;
  const float* src;
  short* dst;
  int C, r0, c0;
  bool isq;
  if (bid < 384) {
    src = (bid < 192) ? Wq1 : Wq2;
    dst = (bid < 192) ? W1t : W2t;
    int tb = bid % 192;
    C = 1536; isq = true;
    r0 = (tb / 24) * 64; c0 = (tb % 24) * 64;
  } else {
    src = Wo; dst = Wot;
    int tb = bid - 384;
    C = 512; isq = false;
    r0 = (tb / 8) * 64; c0 = (tb % 8) * 64;
  }
  const int tid = threadIdx.x;
  const int lr = tid >> 4, lc = (tid & 15) * 4;
#pragma unroll
  for (int i = 0; i < 4; ++i) {
    float4 v = *(const float4*)&src[(size_t)(r0 + lr + 16 * i) * C + c0 + lc];
    t[lr + 16 * i][lc + 0] = v.x;
    t[lr + 16 * i][lc + 1] = v.y;
    t[lr + 16 * i][lc + 2] = v.z;
    t[lr + 16 * i][lc + 3] = v.w;
  }
  __syncthreads();
  const int oc = tid >> 2, orr = (tid & 3) * 16;
  const float sc = (isq && (c0 + oc) < 512) ? SCALE_F : 1.0f;
  short* dbase = dst + (size_t)(c0 + oc) * 512 + r0 + orr;
#pragma unroll
  for (int jj = 0; jj < 4; ++jj) {
    s16x4 ov;
    ov.x = f2bf(t[orr + 4 * jj + 0][oc] * sc);
    ov.y = f2bf(t[orr + 4 * jj + 1][oc] * sc);
    ov.z = f2bf(t[orr + 4 * jj + 2][oc] * sc);
    ov.w = f2bf(t[orr + 4 * jj + 3][oc] * sc);
    *(s16x4*)&dbase[4 * jj] = ov;
  }
}

// ---------------------------------------------------------------------------
// Merged dual-stream QKV GEMM: C = x @ Wqkv for both streams in one launch.
// grid (32, 24): blockIdx.y < 12 -> stream 1, else stream 2.
__global__ __launch_bounds__(256) void gemm_qkv(
    const short* __restrict__ xb1, const short* __restrict__ xb2,
    const short* __restrict__ W1t, const short* __restrict__ W2t,
    short* __restrict__ QK1, short* __restrict__ QK2,
    short* __restrict__ Vt1, short* __restrict__ Vt2) {
  __shared__ short As[128 * 64];
  __shared__ short Bs[128 * 64];
  const int tid = threadIdx.x;
  const int w = tid >> 6, l = tid & 63;
  const int sid = blockIdx.y >= 12;
  const short* A = sid ? xb2 : xb1;
  const short* Bt = sid ? W2t : W1t;
  short* C0 = sid ? QK2 : QK1;
  short* C1 = sid ? Vt2 : Vt1;
  const int m0 = blockIdx.x * 128;
  const int n0 = (sid ? blockIdx.y - 12 : blockIdx.y) * 128;
  const int mi = (w >> 1) * 64, ni = (w & 1) * 64;
  const int lrow = l & 15, lk8 = (l >> 4) * 8;
  const int K = 512;

  f32x4 acc[4][4] = {};

  for (int k0 = 0; k0 < K; k0 += 64) {
    for (int g = 0; g < 4; ++g) {
      int c = g * 256 + w * 64 + l;
      int row = c >> 3, c8 = (c & 7) * 8;
      int ldsoff = (g * 256 + w * 64) * 8;
      gld_lds16(A + (size_t)(m0 + row) * K + k0 + c8, (void*)(As + ldsoff));
      gld_lds16(Bt + (size_t)(n0 + row) * K + k0 + c8, (void*)(Bs + ldsoff));
    }
    __syncthreads();
    __builtin_amdgcn_s_setprio(1);
    for (int kp = 0; kp < 2; ++kp) {
      bf16x8 af[4], bfr[4];
      for (int mf = 0; mf < 4; ++mf)
        af[mf] = *(const bf16x8*)&As[(mi + mf * 16 + lrow) * 64 + kp * 32 + lk8];
      for (int nf = 0; nf < 4; ++nf)
        bfr[nf] = *(const bf16x8*)&Bs[(ni + nf * 16 + lrow) * 64 + kp * 32 + lk8];
      for (int mf = 0; mf < 4; ++mf)
        for (int nf = 0; nf < 4; ++nf)
          acc[mf][nf] = MFMA(af[mf], bfr[nf], acc[mf][nf]);
    }
    __builtin_amdgcn_s_setprio(0);
    __syncthreads();
  }

  for (int mf = 0; mf < 4; ++mf)
    for (int nf = 0; nf < 4; ++nf)
      for (int r = 0; r < 4; ++r) {
        int row = m0 + mi + mf * 16 + (l >> 4) * 4 + r;
        int col = n0 + ni + nf * 16 + lrow;
        float v = acc[mf][nf][r];
        if (col < 1024) {
          C0[(size_t)row * 1024 + col] = f2bf(v);
        } else {
          int b = row >> 11, n = row & 2047;
          int cv = col - 1024, h = cv >> 6, d = cv & 63;
          C1[(((size_t)(b * 8 + h) * 64 + d) << 11) + n] = f2bf(v);
        }
      }
}

// ---------------------------------------------------------------------------
// Output-projection GEMM, 64x128 tile (512 blocks -> 2 blocks/CU):
// Cf[8192,512] = A[8192,512] @ Wot[512,512]^T + bias
__global__ __launch_bounds__(256) void gemm_out(const short* __restrict__ A,
                                                const short* __restrict__ Bt,
                                                float* __restrict__ Cf,
                                                const float* __restrict__ bias) {
  __shared__ short As[64 * 64];
  __shared__ short Bs[128 * 64];
  const int tid = threadIdx.x;
  const int w = tid >> 6, l = tid & 63;
  const int m0 = blockIdx.x * 64, n0 = blockIdx.y * 128;
  const int mi = (w >> 1) * 32, ni = (w & 1) * 64;
  const int lrow = l & 15, lk8 = (l >> 4) * 8;
  const int K = 512, N = 512;

  f32x4 acc[2][4] = {};

  for (int k0 = 0; k0 < K; k0 += 64) {
    for (int g = 0; g < 2; ++g) {
      int c = g * 256 + tid;
      int row = c >> 3, c8 = (c & 7) * 8;
      gld_lds16(A + (size_t)(m0 + row) * K + k0 + c8, (void*)(As + c * 8));
    }
    for (int g = 0; g < 4; ++g) {
      int c = g * 256 + tid;
      int row = c >> 3, c8 = (c & 7) * 8;
      gld_lds16(Bt + (size_t)(n0 + row) * K + k0 + c8, (void*)(Bs + c * 8));
    }
    __syncthreads();
    __builtin_amdgcn_s_setprio(1);
    for (int kp = 0; kp < 2; ++kp) {
      bf16x8 af[2], bfr[4];
      for (int mf = 0; mf < 2; ++mf)
        af[mf] = *(const bf16x8*)&As[(mi + mf * 16 + lrow) * 64 + kp * 32 + lk8];
      for (int nf = 0; nf < 4; ++nf)
        bfr[nf] = *(const bf16x8*)&Bs[(ni + nf * 16 + lrow) * 64 + kp * 32 + lk8];
      for (int mf = 0; mf < 2; ++mf)
        for (int nf = 0; nf < 4; ++nf)
          acc[mf][nf] = MFMA(af[mf], bfr[nf], acc[mf][nf]);
    }
    __builtin_amdgcn_s_setprio(0);
    __syncthreads();
  }

  for (int mf = 0; mf < 2; ++mf)
    for (int nf = 0; nf < 4; ++nf)
      for (int r = 0; r < 4; ++r) {
        int row = m0 + mi + mf * 16 + (l >> 4) * 4 + r;
        int col = n0 + ni + nf * 16 + lrow;
        Cf[(size_t)row * N + col] = acc[mf][nf][r] + bias[col];
      }
}

// ---------------------------------------------------------------------------
// Dual-stream flash attention, v10: cross-iteration pipeline. Each iter runs
// QK(t+1) BEFORE SM(t)/PV(t) (S carried in regs), so QK's MFMAs overlap the
// softmax VALU chain. Staging 2-deep: K(t+2) at iter top (post publish
// barrier), V(t+2) at iter bottom (post drain barrier) -> same 2 LDS buffers,
// still 2 barriers/iter, vmcnt(4) counted waits. Rest identical to v9.
__global__ __launch_bounds__(256, 2) void attn_kernel(
    const short* __restrict__ QK1, const short* __restrict__ QK2,
    const short* __restrict__ Vt1, const short* __restrict__ Vt2,
    short* __restrict__ Ocat) {
  __shared__ short lds[32768];  // 64KB: K1[2][4096] K2 V1 V2 (shorts)
  short* K1s = lds;
  short* K2s = lds + 8192;
  short* V1s = lds + 16384;
  short* V2s = lds + 24576;

  const int tid = threadIdx.x;
  const int w = tid >> 6, l = tid & 63;
  const int wq = w & 1, wk = w >> 1;
  const int lq = l & 31, hi = l >> 5;
  const int qb = blockIdx.x, bh = blockIdx.y;
  const int b = bh >> 3, h = bh & 7;

  const short* Q1p = QK1 + (size_t)b * 2048 * 1024 + h * 64;
  const short* K1p = Q1p + 512;
  const short* Q2p = QK2 + (size_t)b * 2048 * 1024 + h * 64;
  const short* K2p = Q2p + 512;
  const short* V1p = Vt1 + (size_t)bh * 64 * 2048;
  const short* V2p = Vt2 + (size_t)bh * 64 * 2048;

  // Q fragments: lane holds Q[q=lq][d = 16*ck + 8*hi + j]
  const int qrow = qb * 64 + wq * 32 + lq;
  bf16x8 q1f[4], q2f[4];
#pragma unroll
  for (int ck = 0; ck < 4; ++ck) {
    q1f[ck] = *(const bf16x8*)&Q1p[(size_t)qrow * 1024 + ck * 16 + hi * 8];
    q2f[ck] = *(const bf16x8*)&Q2p[(size_t)qrow * 1024 + ck * 16 + hi * 8];
  }

  f32x16 o1a = {}, o1b = {}, o2a = {}, o2b = {};
  float mrun = -1e30f, lrun = 0.f;

  auto stage_K = [&](int buf, int kt) {
    const int kv0 = kt * 64;
#pragma unroll
    for (int gg = 0; gg < 2; ++gg) {
      int cl = gg * 256 + tid;
      int row = cl >> 3;
      int lc = (cl & 7) ^ (row & 7);
      int lr = row & 31;
      int krow = kv0 + ((row >> 5) << 5) + (((lr >> 3) & 1) << 4) +
                 (((lr >> 2) & 1) << 3) + (((lr >> 4) & 1) << 2) + (lr & 3);
      int doff = buf * 4096 + cl * 8;
      gld_lds16(K1p + (size_t)krow * 1024 + lc * 8, (void*)(K1s + doff));
      gld_lds16(K2p + (size_t)krow * 1024 + lc * 8, (void*)(K2s + doff));
    }
  };
  auto stage_V = [&](int buf, int kt) {
    const int kv0 = kt * 64;
#pragma unroll
    for (int gg = 0; gg < 2; ++gg) {
      int cl = gg * 256 + tid;
      int row = cl >> 3;
      int lc = (cl & 7) ^ (row & 7);
      int doff = buf * 4096 + cl * 8;
      gld_lds16(V1p + (size_t)row * 2048 + kv0 + lc * 8, (void*)(V1s + doff));
      gld_lds16(V2p + (size_t)row * 2048 + kv0 + lc * 8, (void*)(V2s + doff));
    }
  };
  auto swo = [&](int row, int kc) { return row * 64 + ((kc ^ (row & 7)) * 8); };

  auto qk_tile = [&](int buf) -> f32x16 {
    const int krd = 32 * wk + lq;
    f32x16 s = {};
    __builtin_amdgcn_s_setprio(1);
#pragma unroll
    for (int ck = 0; ck < 4; ++ck) {
      bf16x8 k1 = *(const bf16x8*)&K1s[buf * 4096 + swo(krd, 2 * ck + hi)];
      bf16x8 k2 = *(const bf16x8*)&K2s[buf * 4096 + swo(krd, 2 * ck + hi)];
      s = MFMA32(k1, q1f[ck], s);
      s = MFMA32(k2, q2f[ck], s);
    }
    __builtin_amdgcn_s_setprio(0);
    return s;
  };

  auto smpv = [&](int buf, f32x16 s) {
    float mx = s[0];
#pragma unroll
    for (int i = 1; i < 16; ++i) mx = fmaxf(mx, s[i]);
    if (!__all(mx - mrun <= 8.0f)) {  // defer-max: rarely fires
      float rm = fmaxf(mx, __shfl_xor(mx, 32));
      float newm = fmaxf(mrun, rm);
      float corr = __expf(mrun - newm);
      mrun = newm;
      lrun *= corr;
#pragma unroll
      for (int i = 0; i < 16; ++i) {
        o1a[i] *= corr; o1b[i] *= corr; o2a[i] *= corr; o2b[i] *= corr;
      }
    }
    float p[16];
#pragma unroll
    for (int i = 0; i < 16; ++i) { p[i] = __expf(s[i] - mrun); lrun += p[i]; }

    __hip_bfloat162 a0 = __float22bfloat162_rn(float2{p[0], p[1]});
    __hip_bfloat162 a1 = __float22bfloat162_rn(float2{p[2], p[3]});
    __hip_bfloat162 a2 = __float22bfloat162_rn(float2{p[8], p[9]});
    __hip_bfloat162 a3 = __float22bfloat162_rn(float2{p[10], p[11]});
    __hip_bfloat162 b0 = __float22bfloat162_rn(float2{p[4], p[5]});
    __hip_bfloat162 b1 = __float22bfloat162_rn(float2{p[6], p[7]});
    __hip_bfloat162 b2 = __float22bfloat162_rn(float2{p[12], p[13]});
    __hip_bfloat162 b3 = __float22bfloat162_rn(float2{p[14], p[15]});
    i32x4 w0 = {*(int*)&a0, *(int*)&a1, *(int*)&a2, *(int*)&a3};
    i32x4 w1 = {*(int*)&b0, *(int*)&b1, *(int*)&b2, *(int*)&b3};
    bf16x8 pb0 = *(bf16x8*)&w0, pb1 = *(bf16x8*)&w1;

    __builtin_amdgcn_s_setprio(1);
#pragma unroll
    for (int c = 0; c < 2; ++c) {
      bf16x8 pb = c ? pb1 : pb0;
      int kcv = 4 * wk + 2 * c + hi;
      bf16x8 v1a = *(const bf16x8*)&V1s[buf * 4096 + swo(lq, kcv)];
      bf16x8 v1b = *(const bf16x8*)&V1s[buf * 4096 + swo(32 + lq, kcv)];
      bf16x8 v2a = *(const bf16x8*)&V2s[buf * 4096 + swo(lq, kcv)];
      bf16x8 v2b = *(const bf16x8*)&V2s[buf * 4096 + swo(32 + lq, kcv)];
      o1a = MFMA32(v1a, pb, o1a);
      o1b = MFMA32(v1b, pb, o1b);
      o2a = MFMA32(v2a, pb, o2a);
      o2b = MFMA32(v2b, pb, o2b);
    }
    __builtin_amdgcn_s_setprio(0);
  };

  // ---- prologue: K0,V0,K1 staged; QK(0); V1 staged ----
  stage_K(0, 0);
  stage_V(0, 0);
  stage_K(1, 1);
  asm volatile("s_waitcnt vmcnt(4)" ::: "memory");  // K0,V0 landed
  __builtin_amdgcn_s_barrier();
  f32x16 sprev = qk_tile(0);
  stage_V(1, 1);

  int cur = 0;
  for (int t = 0; t < 31; ++t) {
    // A: K(t+1) + V(t) landed (allow only V(t+1)'s 4 loads outstanding)
    asm volatile("s_waitcnt vmcnt(4) lgkmcnt(0)" ::: "memory");
    __builtin_amdgcn_s_barrier();
    // B: K(t+2) -> K buf cur (K(t) reads finished last iter, barrier'd)
    if (t < 30) stage_K(cur, t + 2);
    // C: QK(t+1) from K buf cur^1 -- overlaps D's VALU chain
    f32x16 snew = qk_tile(cur ^ 1);
    // D,E: softmax(t) + PV(t) from V buf cur
    smpv(cur, sprev);
    // F: my V(t)/K(t+1) LDS reads done -> publish
    asm volatile("s_waitcnt lgkmcnt(0)" ::: "memory");
    __builtin_amdgcn_s_barrier();
    // G: V(t+2) -> V buf cur (just drained)
    if (t < 30) stage_V(cur, t + 2);
    sprev = snew;
    cur ^= 1;
  }
  // tail: tile 31 (V(31) is the only possibly-outstanding load)
  asm volatile("s_waitcnt vmcnt(0)" ::: "memory");
  __builtin_amdgcn_s_barrier();
  smpv(cur, sprev);

  // ---- cross-wk merge: exact combine of the two kv-half partials ----
  lrun += __shfl_xor(lrun, 32);
  float* cb = (float*)lds;
  float* rg = cb + wq * 4224;  // per-wq region: 4096 O + 64 m + 64 l floats
  if (wk == 1) {
#pragma unroll
    for (int i = 0; i < 16; ++i) {
      rg[i * 64 + l] = o1a[i];
      rg[(16 + i) * 64 + l] = o1b[i];
      rg[(32 + i) * 64 + l] = o2a[i];
      rg[(48 + i) * 64 + l] = o2b[i];
    }
    rg[4096 + l] = mrun;
    rg[4160 + l] = lrun;
  }
  __syncthreads();
  if (wk == 0) {
    float m1 = rg[4096 + l], l1 = rg[4160 + l];
    float mstar = fmaxf(mrun, m1);
    float e0 = __expf(mrun - mstar), e1 = __expf(m1 - mstar);
    float inv = 1.0f / (lrun * e0 + l1 * e1);
    float av0 = e0 * inv, av1 = e1 * inv;
#pragma unroll
    for (int i = 0; i < 16; ++i) {
      o1a[i] = o1a[i] * av0 + rg[i * 64 + l] * av1;
      o1b[i] = o1b[i] * av0 + rg[(16 + i) * 64 + l] * av1;
      o2a[i] = o2a[i] * av0 + rg[(32 + i) * 64 + l] * av1;
      o2b[i] = o2b[i] * av0 + rg[(48 + i) * 64 + l] * av1;
    }
    const size_t base1 = ((size_t)b * 4096 + qrow) * 512 + h * 64;
    const size_t base2 = base1 + (size_t)2048 * 512;
#pragma unroll
    for (int rq = 0; rq < 4; ++rq) {
      int d0 = 8 * rq + 4 * hi;
      s16x4 ov;
      ov.x = f2bf(o1a[rq * 4 + 0]); ov.y = f2bf(o1a[rq * 4 + 1]);
      ov.z = f2bf(o1a[rq * 4 + 2]); ov.w = f2bf(o1a[rq * 4 + 3]);
      *(s16x4*)&Ocat[base1 + d0] = ov;
      ov.x = f2bf(o1b[rq * 4 + 0]); ov.y = f2bf(o1b[rq * 4 + 1]);
      ov.z = f2bf(o1b[rq * 4 + 2]); ov.w = f2bf(o1b[rq * 4 + 3]);
      *(s16x4*)&Ocat[base1 + 32 + d0] = ov;
      ov.x = f2bf(o2a[rq * 4 + 0]); ov.y = f2bf(o2a[rq * 4 + 1]);
      ov.z = f2bf(o2a[rq * 4 + 2]); ov.w = f2bf(o2a[rq * 4 + 3]);
      *(s16x4*)&Ocat[base2 + d0] = ov;
      ov.x = f2bf(o2b[rq * 4 + 0]); ov.y = f2bf(o2b[rq * 4 + 1]);
      ov.z = f2bf(o2b[rq * 4 + 2]); ov.w = f2bf(o2b[rq * 4 + 3]);
      *(s16x4*)&Ocat[base2 + 32 + d0] = ov;
    }
  }
}

// ---------------------------------------------------------------------------
extern "C" void kernel_launch(void* const* d_in, const int* in_sizes, int n_in,
                              void* d_out, int out_size, void* d_ws,
                              size_t ws_size, hipStream_t stream) {
  const float* x1 = (const float*)d_in[0];
  const float* x2 = (const float*)d_in[1];
  const float* Wq1 = (const float*)d_in[2];
  const float* Wq2 = (const float*)d_in[3];
  const float* Wo = (const float*)d_in[4];
  const float* bo = (const float*)d_in[5];
  float* out = (float*)d_out;

  // workspace layout (bf16 elements); total ~45.6 MB
  short* p = (short*)d_ws;
  short* xb1 = p;  p += (size_t)4096 * 512;
  short* xb2 = p;  p += (size_t)4096 * 512;
  short* W1t = p;  p += (size_t)1536 * 512;
  short* W2t = p;  p += (size_t)1536 * 512;
  short* Wot = p;  p += (size_t)512 * 512;
  short* QK1 = p;  p += (size_t)4096 * 1024;
  short* QK2 = p;  p += (size_t)4096 * 1024;
  short* Vt1 = p;  p += (size_t)2 * 8 * 64 * 2048;
  short* Vt2 = p;  p += (size_t)2 * 8 * 64 * 2048;
  short* Ocat = p; p += (size_t)8192 * 512;

  cast_bf16_dual<<<4096, 256, 0, stream>>>(x1, x2, xb1, xb2, 4096 * 512);
  cast_transpose_tiled<<<448, 256, 0, stream>>>(Wq1, Wq2, Wo, W1t, W2t, Wot);

  gemm_qkv<<<dim3(32, 24), 256, 0, stream>>>(xb1, xb2, W1t, W2t, QK1, QK2,
                                             Vt1, Vt2);

  attn_kernel<<<dim3(32, 16), 256, 0, stream>>>(QK1, QK2, Vt1, Vt2, Ocat);

  gemm_out<<<dim3(128, 4), 256, 0, stream>>>(Ocat, Wot, out, bo);
}